// Round 5
// baseline (461.064 us; speedup 1.0000x reference)
//
#include <hip/hip_runtime.h>
#include <hip/hip_bf16.h>
#include <stdint.h>

// Problem constants
#define KD 2304    // K = C*3*3
#define LD 3136    // L = 56*56
#define ND 256     // output channels
#define MD 25088   // B*L
#define CD 256     // input channels
#define PITCH 64   // padded row pitch (floats)
#define PROWS 58
#define PLANE (PROWS * PITCH)   // 3712 floats per padded channel plane

typedef __bf16 bf16x8 __attribute__((ext_vector_type(8)));
typedef float f32x4 __attribute__((ext_vector_type(4)));
typedef float f32x4u __attribute__((ext_vector_type(4), aligned(4)));

__device__ __forceinline__ void gload_lds16(const void* g, void* l) {
  __builtin_amdgcn_global_load_lds(
      (const __attribute__((address_space(1))) unsigned int*)g,
      (__attribute__((address_space(3))) unsigned int*)l, 16, 0, 0);
}

// ---------------- Phase -1: zero-pad x into [B*C][58][PITCH=64] ----------------
__global__ __launch_bounds__(256) void pad_kernel(
    const float* __restrict__ x, float* __restrict__ xpad) {
  const int plane = blockIdx.x;
  const float* src = x + (size_t)plane * LD;
  float* dst = xpad + (size_t)plane * PLANE;
  const int cc4 = (threadIdx.x & 15) * 4;
  const int r0 = threadIdx.x >> 4;
#pragma unroll
  for (int p = 0; p < 4; ++p) {
    const int r = r0 + p * 16;
    if (r >= PROWS) continue;
    f32x4 o = {0.f, 0.f, 0.f, 0.f};
    if (r >= 1 && r <= 56) {
      const float* srow = src + (r - 1) * 56;
      if (cc4 == 0) {
        f32x4u v = *(const f32x4u*)(srow);
        o[1] = v[0]; o[2] = v[1]; o[3] = v[2];
      } else if (cc4 <= 52) {
        o = *(const f32x4u*)(srow + cc4 - 1);
      } else if (cc4 == 56) {
        f32x4u v = *(const f32x4u*)(srow + 52);
        o[0] = v[3];
      }
    }
    *(f32x4*)(dst + r * PITCH + cc4) = o;
  }
}

// ---------------- Phase 0: weight fake-quant -> wqT [N][K] bf16 ----------------
__global__ __launch_bounds__(256) void quant_w_kernel(
    const float* __restrict__ w, __hip_bfloat16* __restrict__ wqT) {
  const int gk = blockIdx.x % 72;
  const int gn = blockIdx.x / 72;
  const int n = gn * 32 + (threadIdx.x >> 3);
  const int k = gk * 32 + (threadIdx.x & 7) * 4;
  const float4 v = *(const float4*)(w + (size_t)n * KD + k);
  float a = fmaxf(fmaxf(fabsf(v.x), fabsf(v.y)), fmaxf(fabsf(v.z), fabsf(v.w)));
#pragma unroll
  for (int m = 1; m <= 32; m <<= 1) a = fmaxf(a, __shfl_xor(a, m, 64));
  __shared__ float red[4];
  if ((threadIdx.x & 63) == 0) red[threadIdx.x >> 6] = a;
  __syncthreads();
  const float mx = fmaxf(fmaxf(red[0], red[1]), fmaxf(red[2], red[3]));
  const float r63 = (mx == 0.f) ? 0.f : 63.f / mx;
  const float scale = mx * (1.f / 63.f);
  ushort4 o;
  o.x = __builtin_bit_cast(unsigned short, __float2bfloat16(rintf(v.x * r63) * scale));
  o.y = __builtin_bit_cast(unsigned short, __float2bfloat16(rintf(v.y * r63) * scale));
  o.z = __builtin_bit_cast(unsigned short, __float2bfloat16(rintf(v.z * r63) * scale));
  o.w = __builtin_bit_cast(unsigned short, __float2bfloat16(rintf(v.w * r63) * scale));
  *(ushort4*)((unsigned short*)wqT + (size_t)n * KD + k) = o;
}

// ---- prefetch window loads for one 32-k granule (static channel/tap phase) ----
template <int KP0>
__device__ __forceinline__ void qload(const float* __restrict__ pb, int p0, int c0,
                                      f32x4u (&win)[5][3]) {
  constexpr int NCH = (KP0 + 31) / 9 + 1;   // 4 or 5 channels touched
#pragma unroll
  for (int dc = 0; dc < 5; ++dc) {
    if (dc >= NCH) continue;
    const int tlo = (dc == 0) ? KP0 : 0;
    const int thi = (dc == NCH - 1) ? (KP0 + 31 - 9 * (NCH - 1)) : 8;
#pragma unroll
    for (int di = 0; di < 3; ++di) {
      if (di >= tlo / 3 && di <= thi / 3)
        win[dc][di] = *(const f32x4u*)(pb + p0 + (c0 + dc) * PLANE + di * PITCH);
    }
  }
}

// ---- finish quant: tree-max, rcp, quant, cvt_pk to bf16, swizzled LDS write ----
template <int KP0>
__device__ __forceinline__ void qfinish(const f32x4u (&win)[5][3],
                                        char* as_row, unsigned cbase, unsigned swz) {
  float v[32];
#pragma unroll
  for (int t = 0; t < 32; ++t) {
    const int idx = KP0 + t;
    v[t] = win[idx / 9][(idx % 9) / 3][(idx % 9) % 3];
  }
  float m16[16];
#pragma unroll
  for (int t = 0; t < 16; ++t)
    m16[t] = fmaxf(__builtin_fabsf(v[2 * t]), __builtin_fabsf(v[2 * t + 1]));
#pragma unroll
  for (int t = 0; t < 8; ++t) m16[t] = fmaxf(m16[t], m16[t + 8]);
#pragma unroll
  for (int t = 0; t < 4; ++t) m16[t] = fmaxf(m16[t], m16[t + 4]);
  const float mx = fmaxf(fmaxf(m16[0], m16[1]), fmaxf(m16[2], m16[3]));
  float r63 = 63.f * __builtin_amdgcn_rcpf(mx);
  r63 = (mx == 0.f) ? 0.f : r63;               // all-zero granule -> q = 0
  const float scale = mx * (1.f / 63.f);
  unsigned pk[16];
#pragma unroll
  for (int t = 0; t < 16; ++t) {
    const float a = rintf(v[2 * t] * r63) * scale;
    const float b = rintf(v[2 * t + 1] * r63) * scale;
    unsigned d;
    asm("v_cvt_pk_bf16_f32 %0, %1, %2" : "=v"(d) : "v"(a), "v"(b));
    pk[t] = d;
  }
#pragma unroll
  for (int s = 0; s < 4; ++s) {
    uint4 o = {pk[4 * s], pk[4 * s + 1], pk[4 * s + 2], pk[4 * s + 3]};
    *(uint4*)(as_row + ((cbase + (unsigned)(s * 16)) ^ swz)) = o;
  }
}

// ---- stage 128x64 wqT tile via global_load_lds (pre-swizzled source) ----
__device__ __forceinline__ void stage_ns(const unsigned short* __restrict__ wsrc,
                                         int k0, int colsw, int lane, int wv,
                                         char* nsDst) {
#pragma unroll
  for (int sg = 0; sg < 8; ++sg) {
    const int seg = sg * 2 + wv;
    const int rowN = seg * 8 + (lane >> 3);
    gload_lds16(wsrc + (size_t)rowN * KD + k0 + colsw,
                nsDst + seg * 1024 + (lane & 7) * 16 + (lane >> 3) * 128);
  }
}

__device__ __forceinline__ void mfma_phase(
    const char* As, const char* Ns,
    f32x4 (&acc)[4][2], int wn, int wm, int lq, int hv, unsigned swq) {
#pragma unroll
  for (int kk = 0; kk < 2; ++kk) {
    const unsigned kobyte = (unsigned)(kk * 64 + hv * 16);
    bf16x8 af[4], bfr[2];
#pragma unroll
    for (int ifr = 0; ifr < 4; ++ifr) {
      const unsigned rn = (unsigned)(wn * 64 + ifr * 16 + lq);
      af[ifr] = *(const bf16x8*)(Ns + (rn * 128u + (kobyte ^ swq)));
    }
#pragma unroll
    for (int jfr = 0; jfr < 2; ++jfr) {
      const unsigned rm = (unsigned)(wm * 32 + jfr * 16 + lq);
      bfr[jfr] = *(const bf16x8*)(As + (rm * 128u + (kobyte ^ swq)));
    }
#pragma unroll
    for (int ifr = 0; ifr < 4; ++ifr)
#pragma unroll
      for (int jfr = 0; jfr < 2; ++jfr)
        acc[ifr][jfr] = __builtin_amdgcn_mfma_f32_16x16x32_bf16(
            af[ifr], bfr[jfr], acc[ifr][jfr], 0, 0, 0);
  }
}

// ---------------- Fused: unfold+quant-A + B-stage + GEMM + bias ----------------
// BM=64, BN=128, BK=64, 4 waves, double-buffered, ONE barrier per K-step:
// step s: prefetch s+1 (quant window loads / gload_lds into buf^1), MFMA buf s,
// finish quant s+1 (VALU) after MFMA, barrier. Roles rotate across blocks.
__global__ __launch_bounds__(256, 3) void fused_gemm_kernel(
    const float* __restrict__ xpad, const __hip_bfloat16* __restrict__ wqT,
    const float* __restrict__ bias, float* __restrict__ out) {
  __shared__ __hip_bfloat16 As[2][64 * 64];     // 2 x 8KB
  __shared__ __hip_bfloat16 Ns[2][128 * 64];    // 2 x 16KB
  const int tid = threadIdx.x;
  const int lane = tid & 63;
  const int w = tid >> 6;                 // output-tile wave id (fixed)
  const int bid = blockIdx.x;             // 0..783
  const int role = (w + bid) & 3;         // staging role, rotated per block

  const int swzb = (bid & 7) * 98 + (bid >> 3);   // XCD swizzle (784%8==0)
  const int mt = swzb >> 1;
  const int nt = swzb & 1;
  const int m0 = mt * 64;
  const int n1 = nt * 128;

  // quant geometry (roles 0,1): row = lane; tile never straddles images
  const int gm = m0 + lane;
  const int b = gm / LD;
  const int l = gm - b * LD;
  const int i = l / 56;
  const int j = l - i * 56;
  const float* pb = xpad + (size_t)b * CD * PLANE;
  const int p0 = i * PITCH + j;
  const unsigned swz_w = (unsigned)((lane & 7) << 4);
  const unsigned cbase = (unsigned)((role & 1) * 64);   // k-half in bytes

  // B-stage geometry (roles 2,3)
  const int colsw = ((lane & 7) ^ (lane >> 3)) * 8;
  const unsigned short* wsrc = (const unsigned short*)wqT + (size_t)n1 * KD;

  // MFMA geometry (by w, not role)
  const int lq = lane & 15, hv = lane >> 4;
  const int wn = w & 1, wm = w >> 1;
  const unsigned swq = (unsigned)((lq & 7) << 4);

  f32x4 acc[4][2] = {};

  // ---- prologue: prep step 0 into buf 0 (phase RP=0: KP0 {0,5}, c0 {0,3}) ----
  {
    f32x4u win[5][3];
    if (role == 0) {
      qload<0>(pb, p0, 0, win);
      qfinish<0>(win, (char*)As[0] + lane * 128, 0u, swz_w);
    } else if (role == 1) {
      qload<5>(pb, p0, 3, win);
      qfinish<5>(win, (char*)As[0] + lane * 128, 64u, swz_w);
    } else {
      stage_ns(wsrc, 0, colsw, lane, role - 2, (char*)Ns[0]);
    }
  }
  __syncthreads();

#define STEP(r)                                                                 \
  {                                                                             \
    const int p = (a + (r)) & 1;                                                \
    const bool dp = !(last && (r) == 8);                                        \
    f32x4u win[5][3];                                                           \
    if (dp) {                                                                   \
      if (role == 0)                                                            \
        qload<(64 * ((r) + 1)) % 9>(pb, p0, cb + (64 * ((r) + 1)) / 9, win);    \
      else if (role == 1)                                                       \
        qload<(64 * ((r) + 1) + 32) % 9>(pb, p0,                                \
                                         cb + (64 * ((r) + 1) + 32) / 9, win);  \
      else                                                                      \
        stage_ns(wsrc, cb * 9 + 64 * ((r) + 1), colsw, lane, role - 2,          \
                 (char*)Ns[p ^ 1]);                                             \
    }                                                                           \
    mfma_phase((const char*)As[p], (const char*)Ns[p], acc, wn, wm, lq, hv,     \
               swq);                                                            \
    if (dp && role < 2) {                                                       \
      if (role == 0)                                                            \
        qfinish<(64 * ((r) + 1)) % 9>(win, (char*)As[p ^ 1] + lane * 128, 0u,   \
                                      swz_w);                                   \
      else                                                                      \
        qfinish<(64 * ((r) + 1) + 32) % 9>(                                     \
            win, (char*)As[p ^ 1] + lane * 128, 64u, swz_w);                    \
    }                                                                           \
    __syncthreads();                                                            \
  }

  int cb = 0;  // 64 * super
  for (int a = 0; a < 4; ++a, cb += 64) {
    const bool last = (a == 3);
    STEP(0) STEP(1) STEP(2) STEP(3) STEP(4) STEP(5) STEP(6) STEP(7) STEP(8)
  }
#undef STEP

  // ---- Epilogue: D row = n, col = m (coalesced along l) ----
#pragma unroll
  for (int ifr = 0; ifr < 4; ++ifr) {
    const int nb = n1 + wn * 64 + ifr * 16 + hv * 4;
    const float4 b4 = *(const float4*)&bias[nb];
#pragma unroll
    for (int jfr = 0; jfr < 2; ++jfr) {
      const int m = m0 + wm * 32 + jfr * 16 + lq;
      const int ll = m - b * LD;
      float* op = out + ((size_t)b * ND + nb) * LD + ll;
      op[0]      = acc[ifr][jfr].x + b4.x;
      op[LD]     = acc[ifr][jfr].y + b4.y;
      op[2 * LD] = acc[ifr][jfr].z + b4.z;
      op[3 * LD] = acc[ifr][jfr].w + b4.w;
    }
  }
}

extern "C" void kernel_launch(void* const* d_in, const int* in_sizes, int n_in,
                              void* d_out, int out_size, void* d_ws, size_t ws_size,
                              hipStream_t stream) {
  const float* x = (const float*)d_in[0];
  const float* wgt = (const float*)d_in[1];
  const float* bias = (const float*)d_in[2];
  float* out = (float*)d_out;

  float* xpad = (float*)d_ws;                         // 8*256*3712*4 = 30,408,704 B
  __hip_bfloat16* wqT = (__hip_bfloat16*)((char*)d_ws + 30408704);  // 1,179,648 B

  pad_kernel<<<8 * CD, 256, 0, stream>>>(x, xpad);
  quant_w_kernel<<<576, 256, 0, stream>>>(wgt, wqT);
  fused_gemm_kernel<<<MD / 64 * 2, 256, 0, stream>>>(xpad, wqT, bias, out);
}

// Round 6
// 79.645 us; speedup vs baseline: 5.7890x; 5.7890x over previous
//
#include <hip/hip_runtime.h>
#include <hip/hip_bf16.h>
#include <stdint.h>

// Problem constants
#define KD 2304    // K = C*3*3
#define LD 3136    // L = 56*56
#define ND 256     // output channels
#define MD 25088   // B*L
#define CD 256     // input channels
#define PITCH 64   // padded row pitch (floats)
#define PROWS 58
#define PLANE (PROWS * PITCH)   // 3712 floats per padded channel plane

typedef __bf16 bf16x8 __attribute__((ext_vector_type(8)));
typedef float f32x4 __attribute__((ext_vector_type(4)));
typedef float f32x4u __attribute__((ext_vector_type(4), aligned(4)));

__device__ __forceinline__ void gload_lds16(const void* g, void* l) {
  __builtin_amdgcn_global_load_lds(
      (const __attribute__((address_space(1))) unsigned int*)g,
      (__attribute__((address_space(3))) unsigned int*)l, 16, 0, 0);
}

// ---------------- Phase -1: zero-pad x into [B*C][58][PITCH=64] ----------------
__global__ __launch_bounds__(256) void pad_kernel(
    const float* __restrict__ x, float* __restrict__ xpad) {
  const int plane = blockIdx.x;
  const float* src = x + (size_t)plane * LD;
  float* dst = xpad + (size_t)plane * PLANE;
  const int cc4 = (threadIdx.x & 15) * 4;
  const int r0 = threadIdx.x >> 4;
#pragma unroll
  for (int p = 0; p < 4; ++p) {
    const int r = r0 + p * 16;
    if (r >= PROWS) continue;
    f32x4 o = {0.f, 0.f, 0.f, 0.f};
    if (r >= 1 && r <= 56) {
      const float* srow = src + (r - 1) * 56;
      if (cc4 == 0) {
        f32x4u v = *(const f32x4u*)(srow);
        o[1] = v[0]; o[2] = v[1]; o[3] = v[2];
      } else if (cc4 <= 52) {
        o = *(const f32x4u*)(srow + cc4 - 1);
      } else if (cc4 == 56) {
        f32x4u v = *(const f32x4u*)(srow + 52);
        o[0] = v[3];
      }
    }
    *(f32x4*)(dst + r * PITCH + cc4) = o;
  }
}

// ---------------- Phase 0: weight fake-quant -> wqT [N][K] bf16 ----------------
__global__ __launch_bounds__(256) void quant_w_kernel(
    const float* __restrict__ w, __hip_bfloat16* __restrict__ wqT) {
  const int gk = blockIdx.x % 72;
  const int gn = blockIdx.x / 72;
  const int n = gn * 32 + (threadIdx.x >> 3);
  const int k = gk * 32 + (threadIdx.x & 7) * 4;
  const float4 v = *(const float4*)(w + (size_t)n * KD + k);
  float a = fmaxf(fmaxf(fabsf(v.x), fabsf(v.y)), fmaxf(fabsf(v.z), fabsf(v.w)));
#pragma unroll
  for (int m = 1; m <= 32; m <<= 1) a = fmaxf(a, __shfl_xor(a, m, 64));
  __shared__ float red[4];
  if ((threadIdx.x & 63) == 0) red[threadIdx.x >> 6] = a;
  __syncthreads();
  const float mx = fmaxf(fmaxf(red[0], red[1]), fmaxf(red[2], red[3]));
  const float r63 = (mx == 0.f) ? 0.f : 63.f / mx;
  const float scale = mx * (1.f / 63.f);
  ushort4 o;
  o.x = __builtin_bit_cast(unsigned short, __float2bfloat16(rintf(v.x * r63) * scale));
  o.y = __builtin_bit_cast(unsigned short, __float2bfloat16(rintf(v.y * r63) * scale));
  o.z = __builtin_bit_cast(unsigned short, __float2bfloat16(rintf(v.z * r63) * scale));
  o.w = __builtin_bit_cast(unsigned short, __float2bfloat16(rintf(v.w * r63) * scale));
  *(ushort4*)((unsigned short*)wqT + (size_t)n * KD + k) = o;
}

// ---- prefetch window loads for one 32-k granule (static channel/tap phase) ----
template <int KP0>
__device__ __forceinline__ void qload(const float* __restrict__ pb, int p0, int c0,
                                      f32x4u (&win)[5][3]) {
  constexpr int NCH = (KP0 + 31) / 9 + 1;   // 4 or 5 channels touched
#pragma unroll
  for (int dc = 0; dc < 5; ++dc) {
    if (dc >= NCH) continue;
    const int tlo = (dc == 0) ? KP0 : 0;
    const int thi = (dc == NCH - 1) ? (KP0 + 31 - 9 * (NCH - 1)) : 8;
#pragma unroll
    for (int di = 0; di < 3; ++di) {
      if (di >= tlo / 3 && di <= thi / 3)
        win[dc][di] = *(const f32x4u*)(pb + p0 + (c0 + dc) * PLANE + di * PITCH);
    }
  }
}

// ---- finish quant: tree-max, rcp, quant, cvt_pk to bf16, swizzled LDS write ----
// as_row = As + lane*256 (256B rows); cbase = w*64 bytes (granule w -> units 4w..4w+3)
template <int KP0>
__device__ __forceinline__ void qfinish(const f32x4u (&win)[5][3],
                                        char* as_row, unsigned cbase, unsigned swz) {
  float v[32];
#pragma unroll
  for (int t = 0; t < 32; ++t) {
    const int idx = KP0 + t;
    v[t] = win[idx / 9][(idx % 9) / 3][(idx % 9) % 3];
  }
  float m16[16];
#pragma unroll
  for (int t = 0; t < 16; ++t)
    m16[t] = fmaxf(__builtin_fabsf(v[2 * t]), __builtin_fabsf(v[2 * t + 1]));
#pragma unroll
  for (int t = 0; t < 8; ++t) m16[t] = fmaxf(m16[t], m16[t + 8]);
#pragma unroll
  for (int t = 0; t < 4; ++t) m16[t] = fmaxf(m16[t], m16[t + 4]);
  const float mx = fmaxf(fmaxf(m16[0], m16[1]), fmaxf(m16[2], m16[3]));
  float r63 = 63.f * __builtin_amdgcn_rcpf(mx);
  r63 = (mx == 0.f) ? 0.f : r63;
  const float scale = mx * (1.f / 63.f);
  unsigned pk[16];
#pragma unroll
  for (int t = 0; t < 16; ++t) {
    const float a = rintf(v[2 * t] * r63) * scale;
    const float b = rintf(v[2 * t + 1] * r63) * scale;
    unsigned d;
    asm("v_cvt_pk_bf16_f32 %0, %1, %2" : "=v"(d) : "v"(a), "v"(b));
    pk[t] = d;
  }
#pragma unroll
  for (int s = 0; s < 4; ++s) {
    uint4 o = {pk[4 * s], pk[4 * s + 1], pk[4 * s + 2], pk[4 * s + 3]};
    *(uint4*)(as_row + ((cbase + (unsigned)(s * 16)) ^ swz)) = o;
  }
}

// ---- stage 256x128 wqT tile via global_load_lds (pre-swizzled source) ----
// Rows are 256B in LDS; swizzle: 16B-unit u at (row) holds source unit u^(row&7).
__device__ __forceinline__ void stage_ns(const unsigned short* __restrict__ wsrc,
                                         int k0, int lane, int w, char* Ns) {
#pragma unroll
  for (int sg = 0; sg < 16; ++sg) {
    const int c = w * 16 + sg;                 // 1KB chunk id (4 rows)
    const int rowN = c * 4 + (lane >> 4);
    const int u = (lane & 15) ^ (rowN & 7);
    gload_lds16(wsrc + (size_t)rowN * KD + k0 + u * 8,
                Ns + c * 1024 + lane * 16);
  }
}

__device__ __forceinline__ void mfma_phase(const char* As, const char* Ns,
                                           f32x4 (&acc)[4][4], int w, int lq, int hv) {
  const unsigned swq = (unsigned)((lq & 7) << 4);
#pragma unroll
  for (int kk = 0; kk < 4; ++kk) {
    const unsigned ko = (unsigned)(kk * 64 + hv * 16);
    bf16x8 af[4], bfr[4];
#pragma unroll
    for (int ifr = 0; ifr < 4; ++ifr) {
      const unsigned rn = (unsigned)(w * 64 + ifr * 16 + lq);
      af[ifr] = *(const bf16x8*)(Ns + rn * 256u + (ko ^ swq));
    }
#pragma unroll
    for (int jfr = 0; jfr < 4; ++jfr) {
      const unsigned rm = (unsigned)(jfr * 16 + lq);
      bfr[jfr] = *(const bf16x8*)(As + rm * 256u + (ko ^ swq));
    }
#pragma unroll
    for (int ifr = 0; ifr < 4; ++ifr)
#pragma unroll
      for (int jfr = 0; jfr < 4; ++jfr)
        acc[ifr][jfr] = __builtin_amdgcn_mfma_f32_16x16x32_bf16(
            af[ifr], bfr[jfr], acc[ifr][jfr], 0, 0, 0);
  }
}

// phase of granule (step R, wave W): KP0 = (128R + 32W) % 9, period 9 in R
#define PH(RR, W) ((128 * (RR) + 32 * (W)) % 9)

// ---------------- Fused: unfold+quant-A + B-stage + GEMM + bias ----------------
// BM=64, BN=256 (=N: every granule quantized once), BK=128, 4 waves.
// Per step: all waves {stage Ns (async gload_lds), qfinish(win)->As, qload next
// win} -> barrier -> MFMA -> barrier. Depth-1 register prefetch of quant loads.
__global__ __launch_bounds__(256, 2) void fused_gemm_kernel(
    const float* __restrict__ xpad, const __hip_bfloat16* __restrict__ wqT,
    const float* __restrict__ bias, float* __restrict__ out) {
  extern __shared__ char smem[];
  char* As = smem;            // 64 rows x 256B  = 16KB (swizzled)
  char* Ns = smem + 16384;    // 256 rows x 256B = 64KB (swizzled via source)
  const int tid = threadIdx.x;
  const int lane = tid & 63;
  const int w = __builtin_amdgcn_readfirstlane(tid >> 6);

  const int bid = blockIdx.x;                    // 0..391
  const int mt = (bid & 7) * 49 + (bid >> 3);    // XCD swizzle: image d -> XCD d
  const int m0 = mt * 64;

  const int b = m0 / LD;                         // uniform (3136 % 64 == 0)
  const int l = m0 - b * LD + lane;
  const int i = l / 56;
  const int j = l - i * 56;
  const float* pb = xpad + (size_t)b * CD * PLANE;
  const int p0 = i * PITCH + j;
  char* as_row = As + lane * 256;
  const unsigned swz = (unsigned)((lane & 7) << 4);
  const unsigned short* wqTu = (const unsigned short*)wqT;

  const int lq = lane & 15, hv = lane >> 4;

  f32x4 acc[4][4] = {};
  f32x4u win[5][3];

#define QLOADX(RS, Rg)                                                        \
  {                                                                           \
    const int c0_ = (128 * (Rg) + 32 * w) / 9;                                \
    switch (w) {                                                              \
      case 0:  qload<PH(RS, 0)>(pb, p0, c0_, win); break;                     \
      case 1:  qload<PH(RS, 1)>(pb, p0, c0_, win); break;                     \
      case 2:  qload<PH(RS, 2)>(pb, p0, c0_, win); break;                     \
      default: qload<PH(RS, 3)>(pb, p0, c0_, win); break;                     \
    }                                                                         \
  }

#define QFINX(RS)                                                             \
  switch (w) {                                                                \
    case 0:  qfinish<PH(RS, 0)>(win, as_row, 0u,   swz); break;               \
    case 1:  qfinish<PH(RS, 1)>(win, as_row, 64u,  swz); break;               \
    case 2:  qfinish<PH(RS, 2)>(win, as_row, 128u, swz); break;               \
    default: qfinish<PH(RS, 3)>(win, as_row, 192u, swz); break;               \
  }

#define STEP(r)                                                               \
  {                                                                           \
    const int Rg = ss9 + (r);                                                 \
    stage_ns(wqTu, Rg * 128, lane, w, Ns);       /* async, drains at bar */   \
    QFINX(r);                                    /* consume win -> As */      \
    if ((r) < 8 || ss == 0) { QLOADX((r) + 1, Rg + 1); } /* prefetch next */  \
    __syncthreads();                                                          \
    mfma_phase(As, Ns, acc, w, lq, hv);                                       \
    __syncthreads();                                                          \
  }

  QLOADX(0, 0);   // prologue: win for step 0

  for (int ss = 0; ss < 2; ++ss) {
    const int ss9 = ss * 9;
    STEP(0) STEP(1) STEP(2) STEP(3) STEP(4) STEP(5) STEP(6) STEP(7) STEP(8)
  }
#undef STEP
#undef QFINX
#undef QLOADX

  // ---- Epilogue: D row = n = w*64 + ifr*16 + hv*4 + comp, col = m ----
#pragma unroll
  for (int ifr = 0; ifr < 4; ++ifr) {
    const int nb = w * 64 + ifr * 16 + hv * 4;
    const float4 b4 = *(const float4*)&bias[nb];
#pragma unroll
    for (int jfr = 0; jfr < 4; ++jfr) {
      const int m = m0 + jfr * 16 + lq;
      const int ll = m - b * LD;
      float* op = out + ((size_t)b * ND + nb) * LD + ll;
      op[0]      = acc[ifr][jfr].x + b4.x;
      op[LD]     = acc[ifr][jfr].y + b4.y;
      op[2 * LD] = acc[ifr][jfr].z + b4.z;
      op[3 * LD] = acc[ifr][jfr].w + b4.w;
    }
  }
}

extern "C" void kernel_launch(void* const* d_in, const int* in_sizes, int n_in,
                              void* d_out, int out_size, void* d_ws, size_t ws_size,
                              hipStream_t stream) {
  const float* x = (const float*)d_in[0];
  const float* wgt = (const float*)d_in[1];
  const float* bias = (const float*)d_in[2];
  float* out = (float*)d_out;

  float* xpad = (float*)d_ws;                         // 8*256*3712*4 = 30,408,704 B
  __hip_bfloat16* wqT = (__hip_bfloat16*)((char*)d_ws + 30408704);  // 1,179,648 B

  pad_kernel<<<8 * CD, 256, 0, stream>>>(x, xpad);
  quant_w_kernel<<<576, 256, 0, stream>>>(wgt, wqT);
  fused_gemm_kernel<<<392, 256, 80 * 1024, stream>>>(xpad, wqT, bias, out);
}

// Round 7
// 77.665 us; speedup vs baseline: 5.9366x; 1.0255x over previous
//
#include <hip/hip_runtime.h>
#include <hip/hip_bf16.h>
#include <stdint.h>

// Problem constants
#define KD 2304    // K = C*3*3
#define LD 3136    // L = 56*56
#define ND 256     // output channels
#define MD 25088   // B*L
#define CD 256     // input channels
#define PITCH 64   // padded row pitch (floats)
#define PROWS 58
#define PLANE (PROWS * PITCH)   // 3712 floats per padded channel plane

typedef __bf16 bf16x8 __attribute__((ext_vector_type(8)));
typedef float f32x4 __attribute__((ext_vector_type(4)));
typedef float f32x4u __attribute__((ext_vector_type(4), aligned(4)));

__device__ __forceinline__ void gload_lds16(const void* g, void* l) {
  __builtin_amdgcn_global_load_lds(
      (const __attribute__((address_space(1))) unsigned int*)g,
      (__attribute__((address_space(3))) unsigned int*)l, 16, 0, 0);
}

// ---------------- Phase -1: zero-pad x into [B*C][58][PITCH=64] ----------------
__global__ __launch_bounds__(256) void pad_kernel(
    const float* __restrict__ x, float* __restrict__ xpad) {
  const int plane = blockIdx.x;
  const float* src = x + (size_t)plane * LD;
  float* dst = xpad + (size_t)plane * PLANE;
  const int cc4 = (threadIdx.x & 15) * 4;
  const int r0 = threadIdx.x >> 4;
#pragma unroll
  for (int p = 0; p < 4; ++p) {
    const int r = r0 + p * 16;
    if (r >= PROWS) continue;
    f32x4 o = {0.f, 0.f, 0.f, 0.f};
    if (r >= 1 && r <= 56) {
      const float* srow = src + (r - 1) * 56;
      if (cc4 == 0) {
        f32x4u v = *(const f32x4u*)(srow);
        o[1] = v[0]; o[2] = v[1]; o[3] = v[2];
      } else if (cc4 <= 52) {
        o = *(const f32x4u*)(srow + cc4 - 1);
      } else if (cc4 == 56) {
        f32x4u v = *(const f32x4u*)(srow + 52);
        o[0] = v[3];
      }
    }
    *(f32x4*)(dst + r * PITCH + cc4) = o;
  }
}

// ---------------- Phase 0: weight fake-quant -> wqT [N][K] bf16 ----------------
__global__ __launch_bounds__(256) void quant_w_kernel(
    const float* __restrict__ w, __hip_bfloat16* __restrict__ wqT) {
  const int gk = blockIdx.x % 72;
  const int gn = blockIdx.x / 72;
  const int n = gn * 32 + (threadIdx.x >> 3);
  const int k = gk * 32 + (threadIdx.x & 7) * 4;
  const float4 v = *(const float4*)(w + (size_t)n * KD + k);
  float a = fmaxf(fmaxf(fabsf(v.x), fabsf(v.y)), fmaxf(fabsf(v.z), fabsf(v.w)));
#pragma unroll
  for (int m = 1; m <= 32; m <<= 1) a = fmaxf(a, __shfl_xor(a, m, 64));
  __shared__ float red[4];
  if ((threadIdx.x & 63) == 0) red[threadIdx.x >> 6] = a;
  __syncthreads();
  const float mx = fmaxf(fmaxf(red[0], red[1]), fmaxf(red[2], red[3]));
  const float r63 = (mx == 0.f) ? 0.f : 63.f / mx;
  const float scale = mx * (1.f / 63.f);
  ushort4 o;
  o.x = __builtin_bit_cast(unsigned short, __float2bfloat16(rintf(v.x * r63) * scale));
  o.y = __builtin_bit_cast(unsigned short, __float2bfloat16(rintf(v.y * r63) * scale));
  o.z = __builtin_bit_cast(unsigned short, __float2bfloat16(rintf(v.z * r63) * scale));
  o.w = __builtin_bit_cast(unsigned short, __float2bfloat16(rintf(v.w * r63) * scale));
  *(ushort4*)((unsigned short*)wqT + (size_t)n * KD + k) = o;
}

// ---- UNIFORM window prefetch: always 5 channels x 3 rows (phase-independent) ----
// Per-channel clamp keeps every load inside the image slab; clamped-duplicate
// planes are only ever read by dummy/tail loads whose values are never used.
__device__ __forceinline__ void qload_u(const float* __restrict__ pb, int p0,
                                        int c0, f32x4u (&win)[5][3]) {
#pragma unroll
  for (int dc = 0; dc < 5; ++dc) {
    const int cdc = (c0 + dc > 255) ? 255 : c0 + dc;
    const float* cp = pb + p0 + cdc * PLANE;
#pragma unroll
    for (int di = 0; di < 3; ++di)
      win[dc][di] = *(const f32x4u*)(cp + di * PITCH);
  }
}

// ---- finish quant: tree-max, rcp, quant, cvt_pk to bf16, swizzled LDS write ----
template <int KP0>
__device__ __forceinline__ void qfinish(const f32x4u (&win)[5][3],
                                        char* as_row, unsigned cbase, unsigned swz) {
  float v[32];
#pragma unroll
  for (int t = 0; t < 32; ++t) {
    const int idx = KP0 + t;
    v[t] = win[idx / 9][(idx % 9) / 3][(idx % 9) % 3];
  }
  float m16[16];
#pragma unroll
  for (int t = 0; t < 16; ++t)
    m16[t] = fmaxf(__builtin_fabsf(v[2 * t]), __builtin_fabsf(v[2 * t + 1]));
#pragma unroll
  for (int t = 0; t < 8; ++t) m16[t] = fmaxf(m16[t], m16[t + 8]);
#pragma unroll
  for (int t = 0; t < 4; ++t) m16[t] = fmaxf(m16[t], m16[t + 4]);
  const float mx = fmaxf(fmaxf(m16[0], m16[1]), fmaxf(m16[2], m16[3]));
  float r63 = 63.f * __builtin_amdgcn_rcpf(mx);
  r63 = (mx == 0.f) ? 0.f : r63;
  const float scale = mx * (1.f / 63.f);
  unsigned pk[16];
#pragma unroll
  for (int t = 0; t < 16; ++t) {
    const float a = rintf(v[2 * t] * r63) * scale;
    const float b = rintf(v[2 * t + 1] * r63) * scale;
    unsigned d;
    asm("v_cvt_pk_bf16_f32 %0, %1, %2" : "=v"(d) : "v"(a), "v"(b));
    pk[t] = d;
  }
#pragma unroll
  for (int s = 0; s < 4; ++s) {
    uint4 o = {pk[4 * s], pk[4 * s + 1], pk[4 * s + 2], pk[4 * s + 3]};
    *(uint4*)(as_row + ((cbase + (unsigned)(s * 16)) ^ swz)) = o;
  }
}

// ---- stage 256x128 wqT tile via global_load_lds (pre-swizzled source) ----
__device__ __forceinline__ void stage_ns(const unsigned short* __restrict__ wsrc,
                                         int k0, int lane, int w, char* Ns) {
#pragma unroll
  for (int sg = 0; sg < 16; ++sg) {
    const int c = w * 16 + sg;                 // 1KB chunk id (4 rows)
    const int rowN = c * 4 + (lane >> 4);
    const int u = (lane & 15) ^ (rowN & 7);
    gload_lds16(wsrc + (size_t)rowN * KD + k0 + u * 8,
                Ns + c * 1024 + lane * 16);
  }
}

__device__ __forceinline__ void mfma_phase(const char* As, const char* Ns,
                                           f32x4 (&acc)[4][4], int w, int lq, int hv) {
  const unsigned swq = (unsigned)((lq & 7) << 4);
#pragma unroll
  for (int kk = 0; kk < 4; ++kk) {
    const unsigned ko = (unsigned)(kk * 64 + hv * 16);
    bf16x8 af[4], bfr[4];
#pragma unroll
    for (int ifr = 0; ifr < 4; ++ifr) {
      const unsigned rn = (unsigned)(w * 64 + ifr * 16 + lq);
      af[ifr] = *(const bf16x8*)(Ns + rn * 256u + (ko ^ swq));
    }
#pragma unroll
    for (int jfr = 0; jfr < 4; ++jfr) {
      const unsigned rm = (unsigned)(jfr * 16 + lq);
      bfr[jfr] = *(const bf16x8*)(As + rm * 256u + (ko ^ swq));
    }
#pragma unroll
    for (int ifr = 0; ifr < 4; ++ifr)
#pragma unroll
      for (int jfr = 0; jfr < 4; ++jfr)
        acc[ifr][jfr] = __builtin_amdgcn_mfma_f32_16x16x32_bf16(
            af[ifr], bfr[jfr], acc[ifr][jfr], 0, 0, 0);
  }
}

// ---------------- Fused: unfold+quant-A + B-stage + GEMM + bias ----------------
// BM=64, BN=256, BK=128, 4 waves. RUNTIME K-loop (18 steps) with a runtime
// 9-case phase switch (I-cache-resident code). Counted-vmcnt barriers keep the
// 15 qload prefetch loads in flight across the barrier (only the 16 gload_lds
// are drained). Dummy final qload keeps the outstanding count uniform.
__global__ __launch_bounds__(256, 2) void fused_gemm_kernel(
    const float* __restrict__ xpad, const __hip_bfloat16* __restrict__ wqT,
    const float* __restrict__ bias, float* __restrict__ out) {
  extern __shared__ char smem[];
  char* As = smem;            // 64 rows x 256B  = 16KB (swizzled)
  char* Ns = smem + 16384;    // 256 rows x 256B = 64KB (swizzled via source)
  const int tid = threadIdx.x;
  const int lane = tid & 63;
  const int w = __builtin_amdgcn_readfirstlane(tid >> 6);

  const int bid = blockIdx.x;                    // 0..391
  const int mt = (bid & 7) * 49 + (bid >> 3);    // XCD swizzle: image d -> XCD d
  const int m0 = mt * 64;

  const int b = m0 / LD;                         // uniform (3136 % 64 == 0)
  const int l = m0 - b * LD + lane;
  const int i = l / 56;
  const int j = l - i * 56;
  const float* pb = xpad + (size_t)b * CD * PLANE;
  const int p0 = i * PITCH + j;
  char* as_row = As + lane * 256;
  const unsigned swz = (unsigned)((lane & 7) << 4);
  const unsigned cbase = (unsigned)(w * 64);
  const unsigned short* wqTu = (const unsigned short*)wqT;

  const int lq = lane & 15, hv = lane >> 4;

  f32x4 acc[4][4] = {};
  f32x4u win[5][3];

  // granule of wave w at step R: g = 4R + w; k = 32g; phase = k % 9; c0 = k / 9
  int kbase = 32 * w;                      // wave-uniform
  int ph = (32 * w) % 9;
  qload_u(pb, p0, kbase / 9, win);         // prologue prefetch (step 0)

  for (int R = 0; R < 18; ++R) {
    stage_ns(wqTu, R * 128, lane, w, Ns);  // 16 async gload_lds -> Ns

    switch (ph) {                          // consume win -> As (wave-uniform branch)
      case 0: qfinish<0>(win, as_row, cbase, swz); break;
      case 1: qfinish<1>(win, as_row, cbase, swz); break;
      case 2: qfinish<2>(win, as_row, cbase, swz); break;
      case 3: qfinish<3>(win, as_row, cbase, swz); break;
      case 4: qfinish<4>(win, as_row, cbase, swz); break;
      case 5: qfinish<5>(win, as_row, cbase, swz); break;
      case 6: qfinish<6>(win, as_row, cbase, swz); break;
      default: qfinish<7>(win, as_row, cbase, swz); break;
      case 8: qfinish<8>(win, as_row, cbase, swz); break;
    }

    // advance to next step's granule and prefetch (dummy on last iter)
    kbase += 128;
    ph += 2; if (ph >= 9) ph -= 9;
    qload_u(pb, p0, kbase / 9, win);       // 15 loads stay in flight past barrier

    asm volatile("s_waitcnt vmcnt(15) lgkmcnt(0)\n\ts_barrier" ::: "memory");
    __builtin_amdgcn_sched_barrier(0);

    mfma_phase(As, Ns, acc, w, lq, hv);

    asm volatile("s_waitcnt lgkmcnt(0)\n\ts_barrier" ::: "memory");
    __builtin_amdgcn_sched_barrier(0);
  }

  // ---- Epilogue: D row = n = w*64 + ifr*16 + hv*4 + comp, col = m ----
#pragma unroll
  for (int ifr = 0; ifr < 4; ++ifr) {
    const int nb = w * 64 + ifr * 16 + hv * 4;
    const float4 b4 = *(const float4*)&bias[nb];
#pragma unroll
    for (int jfr = 0; jfr < 4; ++jfr) {
      const int m = m0 + jfr * 16 + lq;
      const int ll = m - b * LD;
      float* op = out + ((size_t)b * ND + nb) * LD + ll;
      op[0]      = acc[ifr][jfr].x + b4.x;
      op[LD]     = acc[ifr][jfr].y + b4.y;
      op[2 * LD] = acc[ifr][jfr].z + b4.z;
      op[3 * LD] = acc[ifr][jfr].w + b4.w;
    }
  }
}

extern "C" void kernel_launch(void* const* d_in, const int* in_sizes, int n_in,
                              void* d_out, int out_size, void* d_ws, size_t ws_size,
                              hipStream_t stream) {
  const float* x = (const float*)d_in[0];
  const float* wgt = (const float*)d_in[1];
  const float* bias = (const float*)d_in[2];
  float* out = (float*)d_out;

  float* xpad = (float*)d_ws;                         // 8*256*3712*4 = 30,408,704 B
  __hip_bfloat16* wqT = (__hip_bfloat16*)((char*)d_ws + 30408704);  // 1,179,648 B

  pad_kernel<<<8 * CD, 256, 0, stream>>>(x, xpad);
  quant_w_kernel<<<576, 256, 0, stream>>>(wgt, wqT);
  fused_gemm_kernel<<<392, 256, 80 * 1024, stream>>>(xpad, wqT, bias, out);
}